// Round 4
// baseline (27.710 us; speedup 1.0000x reference)
//
#include <hip/hip_runtime.h>
#include <math.h>

#define LMAX 50

typedef short bf16x8 __attribute__((ext_vector_type(8)));
typedef float f32x4  __attribute__((ext_vector_type(4)));

union bfu { bf16x8 v; unsigned u[4]; };

// packed f32 pair -> bf16 pair (RNE), single VALU instr
__device__ __forceinline__ unsigned cvt_pk(float lo, float hi) {
    unsigned r;
    asm("v_cvt_pk_bf16_f32 %0, %1, %2" : "=v"(r) : "v"(lo), "v"(hi));
    return r;
}

__device__ __forceinline__ bf16x8 cvt8f(float4 a, float4 b) {
    bfu r;
    r.u[0] = cvt_pk(a.x, a.y);
    r.u[1] = cvt_pk(a.z, a.w);
    r.u[2] = cvt_pk(b.x, b.y);
    r.u[3] = cvt_pk(b.z, b.w);
    return r.v;
}

// one wave = one batch element; 8 waves/block; all weights live in LDS as
// MFMA B-fragments (nothing weight-persistent in VGPRs -> <=128 VGPR, 4 w/SIMD)
__global__ __launch_bounds__(512, 4) void graphrec_k(
    const float* __restrict__ u_table, const float* __restrict__ i_table,
    const float* __restrict__ W1, const float* __restrict__ b1,
    const float* __restrict__ W2, const float* __restrict__ b2,
    const float* __restrict__ W3, const float* __restrict__ b3,
    const int* __restrict__ nodes, const int* __restrict__ neighbors,
    const int* __restrict__ lengths, float* __restrict__ out)
{
    // frag f: W1 ks0..3 -> f0..15 (ks2..3 = node half), W2 ks0..1 -> f16..23
    __shared__ __attribute__((aligned(16))) short WL[24][64][8];            // 24.5 KB
    __shared__ __attribute__((aligned(16))) unsigned short Hs[8][16 * 72];  // 18.4 KB
    __shared__ float Lg[8][64];                                             //  2 KB

    const int tid  = threadIdx.x;
    const int w    = tid >> 6, lane = tid & 63;
    const int l15  = lane & 15, g = lane >> 4;
    const int g8   = g * 8;

    // ---- stage weights as B-fragments: lane(l15,g) holds B[k][n],
    //      n = nt*16+l15, k = ks*32 + g*8 + i ----
    for (int f = w; f < 24; f += 8) {
        const float* Ws = (f < 16) ? W1 : W2;
        const int    fi = (f < 16) ? f : f - 16;
        const int    ks = fi >> 2, nt = fi & 3;
        const float* p  = Ws + (ks * 32 + g8) * 64 + nt * 16 + l15;
        bfu r;
        r.u[0] = cvt_pk(p[0 * 64], p[1 * 64]);
        r.u[1] = cvt_pk(p[2 * 64], p[3 * 64]);
        r.u[2] = cvt_pk(p[4 * 64], p[5 * 64]);
        r.u[3] = cvt_pk(p[6 * 64], p[7 * 64]);
        *(bf16x8*)&WL[f][lane][0] = r.v;
    }
    __syncthreads();

    float b2v[4], w3v[4];
    #pragma unroll
    for (int nt = 0; nt < 4; ++nt) {
        b2v[nt] = b2[nt * 16 + l15];
        w3v[nt] = W3[nt * 16 + l15];
    }
    // b3 is softmax-invariant; skip.

    const int b     = blockIdx.x * 8 + w;      // one element per wave
    const int len   = lengths[b];              // [1, 50]
    const int node  = nodes[b];
    const int ntile = (len + 15) >> 4;

    // neighbor indices, row-clamped to len-1 (garbage rows masked at logits)
    int idx[6];
    #pragma unroll
    for (int t = 0; t < 6; ++t) idx[t] = 0;
    #pragma unroll
    for (int t = 0; t < 4; ++t) {
        int r = t * 16 + l15; if (r >= len) r = len - 1;
        if (t < ntile) idx[t] = neighbors[b * LMAX + r];
    }

    // node-row loads (issued early)
    const float* up = u_table + node * 64;
    float4 un0 = *(const float4*)(up + g8);
    float4 un1 = *(const float4*)(up + g8 + 4);
    float4 un2 = *(const float4*)(up + 32 + g8);
    float4 un3 = *(const float4*)(up + 32 + g8 + 4);

    float4 LA[2][4];   // 2-deep rolling gather buffers (all indices static)
    #define ISSUE(t) if ((t) < ntile) { \
        const float* xp = i_table + (size_t)idx[t] * 64; \
        LA[(t) & 1][0] = *(const float4*)(xp + g8); \
        LA[(t) & 1][1] = *(const float4*)(xp + g8 + 4); \
        LA[(t) & 1][2] = *(const float4*)(xp + 32 + g8); \
        LA[(t) & 1][3] = *(const float4*)(xp + 32 + g8 + 4); \
    }
    ISSUE(0)
    ISSUE(1)

    // ---- node half of layer 1 (identical for all rows): hn = b1 + xu@W1n ----
    bf16x8 axu0 = cvt8f(un0, un1);
    bf16x8 axu1 = cvt8f(un2, un3);
    f32x4 hn[4];
    #pragma unroll
    for (int nt = 0; nt < 4; ++nt) {
        const float bv = b1[nt * 16 + l15];
        hn[nt] = (f32x4){bv, bv, bv, bv};
    }
    #pragma unroll
    for (int nt = 0; nt < 4; ++nt)
        hn[nt] = __builtin_amdgcn_mfma_f32_16x16x32_bf16(axu0, *(const bf16x8*)&WL[8 + nt][lane][0], hn[nt], 0, 0, 0);
    #pragma unroll
    for (int nt = 0; nt < 4; ++nt)
        hn[nt] = __builtin_amdgcn_mfma_f32_16x16x32_bf16(axu1, *(const bf16x8*)&WL[12 + nt][lane][0], hn[nt], 0, 0, 0);

    float m = -INFINITY;
    unsigned short* hw = &Hs[w][0];

    #define TILE(t) if ((t) < ntile) { \
        bf16x8 a0 = cvt8f(LA[(t) & 1][0], LA[(t) & 1][1]); \
        bf16x8 a1 = cvt8f(LA[(t) & 1][2], LA[(t) & 1][3]); \
        ISSUE((t) + 2) \
        f32x4 acc[4]; \
        _Pragma("unroll") for (int nt = 0; nt < 4; ++nt) acc[nt] = hn[nt]; \
        _Pragma("unroll") for (int nt = 0; nt < 4; ++nt) \
            acc[nt] = __builtin_amdgcn_mfma_f32_16x16x32_bf16(a0, *(const bf16x8*)&WL[nt][lane][0], acc[nt], 0, 0, 0); \
        _Pragma("unroll") for (int nt = 0; nt < 4; ++nt) \
            acc[nt] = __builtin_amdgcn_mfma_f32_16x16x32_bf16(a1, *(const bf16x8*)&WL[4 + nt][lane][0], acc[nt], 0, 0, 0); \
        _Pragma("unroll") for (int nt = 0; nt < 4; ++nt) { \
            unsigned p0 = cvt_pk(fmaxf(acc[nt][0], 0.f), fmaxf(acc[nt][1], 0.f)); \
            unsigned p1 = cvt_pk(fmaxf(acc[nt][2], 0.f), fmaxf(acc[nt][3], 0.f)); \
            hw[(g * 4 + 0) * 72 + nt * 16 + l15] = (unsigned short)p0; \
            hw[(g * 4 + 1) * 72 + nt * 16 + l15] = (unsigned short)(p0 >> 16); \
            hw[(g * 4 + 2) * 72 + nt * 16 + l15] = (unsigned short)p1; \
            hw[(g * 4 + 3) * 72 + nt * 16 + l15] = (unsigned short)(p1 >> 16); \
        } \
        bf16x8 h0 = *(const bf16x8*)&hw[l15 * 72 + g8]; \
        bf16x8 h1 = *(const bf16x8*)&hw[l15 * 72 + 32 + g8]; \
        f32x4 c2[4]; \
        _Pragma("unroll") for (int nt = 0; nt < 4; ++nt) c2[nt] = (f32x4){b2v[nt], b2v[nt], b2v[nt], b2v[nt]}; \
        _Pragma("unroll") for (int nt = 0; nt < 4; ++nt) \
            c2[nt] = __builtin_amdgcn_mfma_f32_16x16x32_bf16(h0, *(const bf16x8*)&WL[16 + nt][lane][0], c2[nt], 0, 0, 0); \
        _Pragma("unroll") for (int nt = 0; nt < 4; ++nt) \
            c2[nt] = __builtin_amdgcn_mfma_f32_16x16x32_bf16(h1, *(const bf16x8*)&WL[20 + nt][lane][0], c2[nt], 0, 0, 0); \
        float sv[4]; \
        _Pragma("unroll") for (int reg = 0; reg < 4; ++reg) { \
            float s = 0.f; \
            _Pragma("unroll") for (int nt = 0; nt < 4; ++nt) \
                s = fmaf(fmaxf(c2[nt][reg], 0.f), w3v[nt], s); \
            s += __shfl_xor(s, 1); s += __shfl_xor(s, 2); \
            s += __shfl_xor(s, 4); s += __shfl_xor(s, 8); \
            if ((t) * 16 + g * 4 + reg >= len) s = -INFINITY; \
            sv[reg] = s; \
        } \
        if (l15 == 0) *(float4*)&Lg[w][(t) * 16 + g * 4] = make_float4(sv[0], sv[1], sv[2], sv[3]); \
        float tm = fmaxf(fmaxf(sv[0], sv[1]), fmaxf(sv[2], sv[3])); \
        tm = fmaxf(tm, __shfl_xor(tm, 16)); \
        tm = fmaxf(tm, __shfl_xor(tm, 32)); \
        m = fmaxf(m, tm); \
    }

    TILE(0)
    TILE(1)
    TILE(2)
    TILE(3)

    // ---- finalize: e = exp(logit - m) recomputed per lane (no reduces);
    //      weighted sum re-gathers rows in f32 (L1/L2-hot) ----
    float ac0 = 0.f, ac1 = 0.f, ac2 = 0.f, ac3 = 0.f, ss = 0.f;
    const int* nb = neighbors + b * LMAX;
    for (int r0 = 0; r0 < len; r0 += 4) {
        float e0 = 0.f, e1 = 0.f, e2 = 0.f, e3 = 0.f;
        float x0 = 0.f, x1 = 0.f, x2 = 0.f, x3 = 0.f;
        { e0 = __expf(Lg[w][r0] - m);     x0 = i_table[(size_t)nb[r0] * 64 + lane]; }
        if (r0 + 1 < len) { e1 = __expf(Lg[w][r0 + 1] - m); x1 = i_table[(size_t)nb[r0 + 1] * 64 + lane]; }
        if (r0 + 2 < len) { e2 = __expf(Lg[w][r0 + 2] - m); x2 = i_table[(size_t)nb[r0 + 2] * 64 + lane]; }
        if (r0 + 3 < len) { e3 = __expf(Lg[w][r0 + 3] - m); x3 = i_table[(size_t)nb[r0 + 3] * 64 + lane]; }
        ss  += (e0 + e1) + (e2 + e3);
        ac0 = fmaf(e0, x0, ac0); ac1 = fmaf(e1, x1, ac1);
        ac2 = fmaf(e2, x2, ac2); ac3 = fmaf(e3, x3, ac3);
    }
    out[b * 64 + lane] = ((ac0 + ac1) + (ac2 + ac3)) / ss;
}

extern "C" void kernel_launch(void* const* d_in, const int* in_sizes, int n_in,
                              void* d_out, int out_size, void* d_ws, size_t ws_size,
                              hipStream_t stream) {
    const float* u_table   = (const float*)d_in[0];
    const float* i_table   = (const float*)d_in[1];
    const float* W1        = (const float*)d_in[2];
    const float* b1        = (const float*)d_in[3];
    const float* W2        = (const float*)d_in[4];
    const float* b2        = (const float*)d_in[5];
    const float* W3        = (const float*)d_in[6];
    const float* b3        = (const float*)d_in[7];
    const int*   nodes     = (const int*)d_in[8];
    const int*   neighbors = (const int*)d_in[9];
    const int*   lengths   = (const int*)d_in[10];
    float* out = (float*)d_out;

    graphrec_k<<<dim3(512), dim3(512), 0, stream>>>(
        u_table, i_table, W1, b1, W2, b2, W3, b3, nodes, neighbors, lengths, out);
}